// Round 6
// baseline (418.434 us; speedup 1.0000x reference)
//
#include <hip/hip_runtime.h>
#include <hip/hip_bf16.h>

typedef __bf16 bf16x8 __attribute__((ext_vector_type(8)));
typedef float f32x4 __attribute__((ext_vector_type(4)));

// Problem constants: B=2, S=2048, D=1024, H=16, HD=64
#define NB 2
#define NS 2048
#define ND 1024
#define NH 16
#define NHD 64

__device__ __forceinline__ unsigned short f2b(float f) {
    union { __hip_bfloat16 h; unsigned short u; } c;
    c.h = __float2bfloat16(f);
    return c.u;
}

// ---------------------------------------------------------------------------
// One-shot f32->bf16 convert of x, Wq, Wk, Wv (merged to save launch gaps).
// ---------------------------------------------------------------------------
__global__ __launch_bounds__(256) void to_bf16_all(
    const float* __restrict__ x,  const float* __restrict__ wq,
    const float* __restrict__ wk, const float* __restrict__ wv,
    unsigned short* __restrict__ xb,  unsigned short* __restrict__ wqb,
    unsigned short* __restrict__ wkb, unsigned short* __restrict__ wvb)
{
    const size_t TX = (size_t)NB * NS * ND / 8;   // 524288 threads for x
    const size_t TW = (size_t)ND * ND / 8;        // 131072 threads per W
    size_t gid = (size_t)blockIdx.x * 256 + threadIdx.x;
    const float* src; unsigned short* dst; size_t off;
    if (gid < TX)               { src = x;  dst = xb;  off = gid * 8; }
    else if (gid < TX + TW)     { src = wq; dst = wqb; off = (gid - TX) * 8; }
    else if (gid < TX + 2 * TW) { src = wk; dst = wkb; off = (gid - TX - TW) * 8; }
    else                        { src = wv; dst = wvb; off = (gid - TX - 2 * TW) * 8; }
    float4 a = *(const float4*)(src + off);
    float4 b = *(const float4*)(src + off + 4);
    alignas(16) unsigned short t[8];
    t[0] = f2b(a.x); t[1] = f2b(a.y); t[2] = f2b(a.z); t[3] = f2b(a.w);
    t[4] = f2b(b.x); t[5] = f2b(b.y); t[6] = f2b(b.z); t[7] = f2b(b.w);
    *(uint4*)(dst + off) = *(const uint4*)t;
}

// ---------------------------------------------------------------------------
// Mask dtype probe. flag = 1 -> 4-byte elements, 0 -> 1-byte.
// ---------------------------------------------------------------------------
__global__ void detect_mask(const unsigned* __restrict__ m, int* __restrict__ flag) {
    __shared__ int bad;
    if (threadIdx.x == 0) bad = 0;
    __syncthreads();
    int mybad = 0;
    for (int i = threadIdx.x; i < 8192; i += 256) {
        unsigned w = m[i];
        if (w != 0u && w != 1u && w != 0x3F800000u) mybad = 1;
    }
    if (mybad) bad = 1;
    __syncthreads();
    if (threadIdx.x == 0) *flag = bad ? 0 : 1;
}

// ---------------------------------------------------------------------------
// Bit-pack the mask: B*S*S elements -> u64 words (1 MB, L2-resident).
// ---------------------------------------------------------------------------
__global__ __launch_bounds__(256) void pack_mask(
    const void* __restrict__ mask, const int* __restrict__ mflag,
    unsigned long long* __restrict__ mbits)
{
    const int wave = threadIdx.x >> 6;
    const int lane = threadIdx.x & 63;
    const size_t w = (size_t)blockIdx.x * 4 + wave;
    const size_t e = w * 64 + lane;
    int v;
    if (*mflag) v = (((const unsigned*)mask)[e] != 0u);
    else        v = (((const unsigned char*)mask)[e] != 0);
    unsigned long long bits = __ballot(v);
    if (lane == 0) mbits[w] = bits;
}

// ---------------------------------------------------------------------------
// QKV projection (unchanged from round 4): y = x @ W.T + b, bf16 inputs.
// Q,K stored [B,H,S,HD] bf16; V stored transposed [B,H,HD,S] bf16.
// ---------------------------------------------------------------------------
__global__ __launch_bounds__(256) void qkv_gemm(
    const unsigned short* __restrict__ xb,
    const unsigned short* __restrict__ Wqb, const float* __restrict__ bq,
    const unsigned short* __restrict__ Wkb, const float* __restrict__ bk,
    const unsigned short* __restrict__ Wvb, const float* __restrict__ bv,
    unsigned short* __restrict__ Qb, unsigned short* __restrict__ Kb,
    unsigned short* __restrict__ Vtb)
{
    __shared__ alignas(16) unsigned short Alds[128][40];
    __shared__ alignas(16) unsigned short Blds[128][40];

    const int tid  = threadIdx.x;
    const int wave = tid >> 6;
    const int lane = tid & 63;
    const int z    = blockIdx.z;

    const unsigned short* W = (z == 0) ? Wqb : (z == 1) ? Wkb : Wvb;
    const float* bias       = (z == 0) ? bq  : (z == 1) ? bk  : bv;

    const int m0 = blockIdx.x * 128;
    const int n0 = blockIdx.y * 128;
    const int wr = (wave >> 1) * 64;
    const int wc = (wave & 1) * 64;

    const int srow = tid >> 1;
    const int scol = (tid & 1) * 16;
    const unsigned short* xsrc = xb + (size_t)(m0 + srow) * ND + scol;
    const unsigned short* wsrc = W  + (size_t)(n0 + srow) * ND + scol;

    const int lg = lane >> 4;
    const int ll = lane & 15;
    const int kcol = lg * 8;

    f32x4 acc[4][4] = {};

    for (int kt = 0; kt < ND; kt += 32) {
        uint4 a0 = *(const uint4*)(xsrc + kt);
        uint4 a1 = *(const uint4*)(xsrc + kt + 8);
        uint4 b0 = *(const uint4*)(wsrc + kt);
        uint4 b1 = *(const uint4*)(wsrc + kt + 8);

        if (kt != 0) __syncthreads();
        *(uint4*)&Alds[srow][scol]     = a0;
        *(uint4*)&Alds[srow][scol + 8] = a1;
        *(uint4*)&Blds[srow][scol]     = b0;
        *(uint4*)&Blds[srow][scol + 8] = b1;
        __syncthreads();

        bf16x8 af[4], bfr[4];
        #pragma unroll
        for (int m = 0; m < 4; m++)
            af[m] = *(const bf16x8*)&Alds[wr + m * 16 + ll][kcol];
        #pragma unroll
        for (int n = 0; n < 4; n++)
            bfr[n] = *(const bf16x8*)&Blds[wc + n * 16 + ll][kcol];

        __builtin_amdgcn_s_setprio(1);
        #pragma unroll
        for (int m = 0; m < 4; m++)
            #pragma unroll
            for (int n = 0; n < 4; n++)
                acc[m][n] = __builtin_amdgcn_mfma_f32_16x16x32_bf16(
                    af[m], bfr[n], acc[m][n], 0, 0, 0);
        __builtin_amdgcn_s_setprio(0);
    }

    #pragma unroll
    for (int n = 0; n < 4; n++) {
        const int j  = n0 + wc + n * 16 + ll;
        const float bj = bias[j];
        const int hh = j >> 6;
        const int hd = j & 63;
        #pragma unroll
        for (int m = 0; m < 4; m++) {
            #pragma unroll
            for (int r = 0; r < 4; r++) {
                const int i  = m0 + wr + m * 16 + lg * 4 + r;
                const int bb = i >> 11;
                const int ss = i & 2047;
                const unsigned short o = f2b(acc[m][n][r] + bj);
                if (z == 2) {
                    Vtb[((size_t)(bb * NH + hh) * NHD + hd) * NS + ss] = o;
                } else {
                    const size_t idx = ((size_t)(bb * NH + hh) * NS + ss) * NHD + hd;
                    if (z == 0) Qb[idx] = o; else Kb[idx] = o;
                }
            }
        }
    }
}

// ---------------------------------------------------------------------------
// Flash attention, swapped-QK^T + defer-max + XCD-local heads + K-prefetch.
// 1-D grid of 1024 WGs: wg&7 selects XCD (HW round-robin); each XCD owns 4
// whole (b,h) heads -> K/V (2MB) stays in that XCD's L2. Next chunk's K
// fragments + mask word are loaded one chunk ahead so QK-MFMA never waits
// on global latency (covered by previous chunk's softmax+PV).
// ---------------------------------------------------------------------------
__global__ __launch_bounds__(256) void attn_kernel(
    const unsigned short* __restrict__ Qb, const unsigned short* __restrict__ Kb,
    const unsigned short* __restrict__ Vtb,
    const unsigned long long* __restrict__ mbits, float* __restrict__ out)
{
    __shared__ alignas(16) unsigned short Plds[4][16][72];

    const int tid  = threadIdx.x;
    const int wave = tid >> 6;
    const int lane = tid & 63;

    // XCD-aware decode: 4 heads per XCD, 32 q-blocks per head.
    const int wg   = blockIdx.x;
    const int xcd  = wg & 7;
    const int slot = wg >> 3;               // 0..127
    const int hb   = xcd * 4 + (slot >> 5); // 0..31
    const int qblk = slot & 31;
    const int h = hb & (NH - 1);
    const int b = hb >> 4;
    const int q0 = qblk * 64 + wave * 16;

    const unsigned short* Qp = Qb  + (size_t)(b * NH + h) * NS * NHD;
    const unsigned short* Kp = Kb  + (size_t)(b * NH + h) * NS * NHD;
    const unsigned short* Vp = Vtb + (size_t)(b * NH + h) * NHD * NS;
    const unsigned long long* mrow = mbits + (size_t)b * NS * (NS / 64);

    const int lg = lane >> 4;
    const int ll = lane & 15;
    const int kcol = lg * 8;

    const bf16x8 qf0 = *(const bf16x8*)&Qp[(q0 + ll) * NHD + kcol];
    const bf16x8 qf1 = *(const bf16x8*)&Qp[(q0 + ll) * NHD + 32 + kcol];

    f32x4 O0 = {}, O1 = {}, O2 = {}, O3 = {};
    float mrun = -3.0e38f;   // running max for q = q0 + ll
    float lrun = 0.f;

    const float scale = 0.03125f;  // 1/sqrt(1024)

    // ---- prologue: chunk 0 K-frags + mask in registers ----
    bf16x8 c00 = *(const bf16x8*)&Kp[(0      + ll) * NHD + kcol];
    bf16x8 c01 = *(const bf16x8*)&Kp[(0      + ll) * NHD + 32 + kcol];
    bf16x8 c10 = *(const bf16x8*)&Kp[(16     + ll) * NHD + kcol];
    bf16x8 c11 = *(const bf16x8*)&Kp[(16     + ll) * NHD + 32 + kcol];
    bf16x8 c20 = *(const bf16x8*)&Kp[(32     + ll) * NHD + kcol];
    bf16x8 c21 = *(const bf16x8*)&Kp[(32     + ll) * NHD + 32 + kcol];
    bf16x8 c30 = *(const bf16x8*)&Kp[(48     + ll) * NHD + kcol];
    bf16x8 c31 = *(const bf16x8*)&Kp[(48     + ll) * NHD + 32 + kcol];
    unsigned long long mwc = mrow[(size_t)(q0 + ll) * (NS / 64)];

    for (int kb = 0; kb < NS; kb += 64) {
        // ---- prefetch next chunk's K + mask (hidden under this chunk) ----
        const int kn = (kb + 64 < NS) ? kb + 64 : 0;
        bf16x8 n00 = *(const bf16x8*)&Kp[(kn      + ll) * NHD + kcol];
        bf16x8 n01 = *(const bf16x8*)&Kp[(kn      + ll) * NHD + 32 + kcol];
        bf16x8 n10 = *(const bf16x8*)&Kp[(kn + 16 + ll) * NHD + kcol];
        bf16x8 n11 = *(const bf16x8*)&Kp[(kn + 16 + ll) * NHD + 32 + kcol];
        bf16x8 n20 = *(const bf16x8*)&Kp[(kn + 32 + ll) * NHD + kcol];
        bf16x8 n21 = *(const bf16x8*)&Kp[(kn + 32 + ll) * NHD + 32 + kcol];
        bf16x8 n30 = *(const bf16x8*)&Kp[(kn + 48 + ll) * NHD + kcol];
        bf16x8 n31 = *(const bf16x8*)&Kp[(kn + 48 + ll) * NHD + 32 + kcol];
        const unsigned long long mwn = mrow[(size_t)(q0 + ll) * (NS / 64) + (kn >> 6)];

        // ---- QK^T swapped (current regs, no memory wait) ----
        f32x4 s0 = {}, s1 = {}, s2 = {}, s3 = {};
        __builtin_amdgcn_s_setprio(1);
        s0 = __builtin_amdgcn_mfma_f32_16x16x32_bf16(c00, qf0, s0, 0, 0, 0);
        s1 = __builtin_amdgcn_mfma_f32_16x16x32_bf16(c10, qf0, s1, 0, 0, 0);
        s2 = __builtin_amdgcn_mfma_f32_16x16x32_bf16(c20, qf0, s2, 0, 0, 0);
        s3 = __builtin_amdgcn_mfma_f32_16x16x32_bf16(c30, qf0, s3, 0, 0, 0);
        s0 = __builtin_amdgcn_mfma_f32_16x16x32_bf16(c01, qf1, s0, 0, 0, 0);
        s1 = __builtin_amdgcn_mfma_f32_16x16x32_bf16(c11, qf1, s1, 0, 0, 0);
        s2 = __builtin_amdgcn_mfma_f32_16x16x32_bf16(c21, qf1, s2, 0, 0, 0);
        s3 = __builtin_amdgcn_mfma_f32_16x16x32_bf16(c31, qf1, s3, 0, 0, 0);
        __builtin_amdgcn_s_setprio(0);

        // ---- V loads (current chunk; latency covered by softmax) ----
        bf16x8 v00 = *(const bf16x8*)&Vp[(size_t)(0 * 16 + ll) * NS + kb + kcol];
        bf16x8 v01 = *(const bf16x8*)&Vp[(size_t)(0 * 16 + ll) * NS + kb + 32 + kcol];
        bf16x8 v10 = *(const bf16x8*)&Vp[(size_t)(1 * 16 + ll) * NS + kb + kcol];
        bf16x8 v11 = *(const bf16x8*)&Vp[(size_t)(1 * 16 + ll) * NS + kb + 32 + kcol];
        bf16x8 v20 = *(const bf16x8*)&Vp[(size_t)(2 * 16 + ll) * NS + kb + kcol];
        bf16x8 v21 = *(const bf16x8*)&Vp[(size_t)(2 * 16 + ll) * NS + kb + 32 + kcol];
        bf16x8 v30 = *(const bf16x8*)&Vp[(size_t)(3 * 16 + ll) * NS + kb + kcol];
        bf16x8 v31 = *(const bf16x8*)&Vp[(size_t)(3 * 16 + ll) * NS + kb + 32 + kcol];

        // ---- scores for q=q0+ll: sv[t*4+r] = score(k = kb + 16t + 4lg + r) ----
        const unsigned long long mws = mwc >> (lg * 4);
        float sv[16];
        #pragma unroll
        for (int t = 0; t < 4; t++) {
            const f32x4 st = (t == 0) ? s0 : (t == 1) ? s1 : (t == 2) ? s2 : s3;
            #pragma unroll
            for (int r = 0; r < 4; r++)
                sv[t * 4 + r] = ((mws >> (16 * t + r)) & 1ull) ? -1e9f
                                                               : st[r] * scale;
        }

        float m01 = fmaxf(fmaxf(sv[0], sv[1]), fmaxf(sv[2], sv[3]));
        float m23 = fmaxf(fmaxf(sv[4], sv[5]), fmaxf(sv[6], sv[7]));
        float m45 = fmaxf(fmaxf(sv[8], sv[9]), fmaxf(sv[10], sv[11]));
        float m67 = fmaxf(fmaxf(sv[12], sv[13]), fmaxf(sv[14], sv[15]));
        float mt = fmaxf(fmaxf(m01, m23), fmaxf(m45, m67));
        mt = fmaxf(mt, __shfl_xor(mt, 16));
        mt = fmaxf(mt, __shfl_xor(mt, 32));

        if (!__all(mt <= mrun + 8.0f)) {
            const float mnew  = fmaxf(mrun, mt);
            const float alpha = __expf(mrun - mnew);
            mrun = mnew;
            lrun *= alpha;
            #pragma unroll
            for (int r = 0; r < 4; r++) {
                const float ar = __shfl(alpha, lg * 4 + r);
                O0[r] *= ar; O1[r] *= ar; O2[r] *= ar; O3[r] *= ar;
            }
        }

        // ---- exp + sum + pack P ----
        float rs = 0.f;
        #pragma unroll
        for (int t = 0; t < 4; t++) {
            const float p0 = __expf(sv[t * 4 + 0] - mrun);
            const float p1 = __expf(sv[t * 4 + 1] - mrun);
            const float p2 = __expf(sv[t * 4 + 2] - mrun);
            const float p3 = __expf(sv[t * 4 + 3] - mrun);
            rs += (p0 + p1) + (p2 + p3);
            uint2 w;
            w.x = (unsigned)f2b(p0) | ((unsigned)f2b(p1) << 16);
            w.y = (unsigned)f2b(p2) | ((unsigned)f2b(p3) << 16);
            *(uint2*)&Plds[wave][ll][t * 16 + lg * 4] = w;
        }
        rs += __shfl_xor(rs, 16);
        rs += __shfl_xor(rs, 32);
        lrun += rs;

        // ---- PV ----
        const bf16x8 pa0 = *(const bf16x8*)&Plds[wave][ll][kcol];
        const bf16x8 pa1 = *(const bf16x8*)&Plds[wave][ll][32 + kcol];
        __builtin_amdgcn_s_setprio(1);
        O0 = __builtin_amdgcn_mfma_f32_16x16x32_bf16(pa0, v00, O0, 0, 0, 0);
        O1 = __builtin_amdgcn_mfma_f32_16x16x32_bf16(pa0, v10, O1, 0, 0, 0);
        O2 = __builtin_amdgcn_mfma_f32_16x16x32_bf16(pa0, v20, O2, 0, 0, 0);
        O3 = __builtin_amdgcn_mfma_f32_16x16x32_bf16(pa0, v30, O3, 0, 0, 0);
        O0 = __builtin_amdgcn_mfma_f32_16x16x32_bf16(pa1, v01, O0, 0, 0, 0);
        O1 = __builtin_amdgcn_mfma_f32_16x16x32_bf16(pa1, v11, O1, 0, 0, 0);
        O2 = __builtin_amdgcn_mfma_f32_16x16x32_bf16(pa1, v21, O2, 0, 0, 0);
        O3 = __builtin_amdgcn_mfma_f32_16x16x32_bf16(pa1, v31, O3, 0, 0, 0);
        __builtin_amdgcn_s_setprio(0);

        // ---- rotate prefetched regs ----
        c00 = n00; c01 = n01; c10 = n10; c11 = n11;
        c20 = n20; c21 = n21; c30 = n30; c31 = n31;
        mwc = mwn;
    }

    #pragma unroll
    for (int r = 0; r < 4; r++) {
        const int q = q0 + lg * 4 + r;
        const float inv = 1.0f / __shfl(lrun, lg * 4 + r);
        float* op = out + (size_t)(b * NS + q) * ND + h * NHD;
        op[0 * 16 + ll] = O0[r] * inv;
        op[1 * 16 + ll] = O1[r] * inv;
        op[2 * 16 + ll] = O2[r] * inv;
        op[3 * 16 + ll] = O3[r] * inv;
    }
}

extern "C" void kernel_launch(void* const* d_in, const int* in_sizes, int n_in,
                              void* d_out, int out_size, void* d_ws, size_t ws_size,
                              hipStream_t stream)
{
    const float* x  = (const float*)d_in[0];
    const void* mask = d_in[1];
    const float* Wq = (const float*)d_in[2];
    const float* bq = (const float*)d_in[3];
    const float* Wk = (const float*)d_in[4];
    const float* bk = (const float*)d_in[5];
    const float* Wv = (const float*)d_in[6];
    const float* bv = (const float*)d_in[7];
    float* out = (float*)d_out;

    const size_t szX = (size_t)NB * NS * ND;              // 4M elems
    const size_t szW = (size_t)ND * ND;                   // 1M elems
    const size_t szQ = (size_t)NB * NH * NS * NHD;        // 4M elems

    int* mflag = (int*)d_ws;
    unsigned short* xb  = (unsigned short*)((char*)d_ws + 256);  // 8MB
    unsigned short* Wqb = xb  + szX;                             // 2MB
    unsigned short* Wkb = Wqb + szW;                             // 2MB
    unsigned short* Wvb = Wkb + szW;                             // 2MB
    unsigned short* Qb  = Wvb + szW;                             // 8MB
    unsigned short* Kb  = Qb + szQ;                              // 8MB
    unsigned short* Vtb = Kb + szQ;                              // 8MB
    unsigned long long* mbits = (unsigned long long*)(Vtb + szQ);// 1MB

    dim3 blk(256);
    const int cvtBlocks = (int)((szX + 3 * szW) / 8 / 256);      // 3584
    to_bf16_all<<<dim3(cvtBlocks), blk, 0, stream>>>(
        x, Wq, Wk, Wv, xb, Wqb, Wkb, Wvb);

    detect_mask<<<dim3(1), blk, 0, stream>>>((const unsigned*)mask, mflag);
    const int words = NB * NS * NS / 64;
    pack_mask<<<dim3(words / 4), blk, 0, stream>>>(mask, mflag, mbits);

    dim3 g1(32, 8, 3);
    qkv_gemm<<<g1, blk, 0, stream>>>(xb, Wqb, bq, Wkb, bk, Wvb, bv, Qb, Kb, Vtb);

    attn_kernel<<<dim3(1024), blk, 0, stream>>>(Qb, Kb, Vtb, mbits, out);
}

// Round 8
// 235.031 us; speedup vs baseline: 1.7803x; 1.7803x over previous
//
#include <hip/hip_runtime.h>
#include <hip/hip_bf16.h>

typedef __bf16 bf16x8 __attribute__((ext_vector_type(8)));
typedef float f32x4 __attribute__((ext_vector_type(4)));

// Problem constants: B=2, S=2048, D=1024, H=16, HD=64
#define NB 2
#define NS 2048
#define ND 1024
#define NH 16
#define NHD 64

__device__ __forceinline__ unsigned short f2b(float f) {
    union { __hip_bfloat16 h; unsigned short u; } c;
    c.h = __float2bfloat16(f);
    return c.u;
}

// Async global->LDS, 16 bytes per lane. LDS dest = wave-uniform base + lane*16.
__device__ __forceinline__ void gl_lds16(const unsigned short* g, unsigned short* l) {
    __builtin_amdgcn_global_load_lds(
        (const __attribute__((address_space(1))) unsigned int*)g,
        (__attribute__((address_space(3))) unsigned int*)l, 16, 0, 0);
}

// ---------------------------------------------------------------------------
// One-shot f32->bf16 convert of x, Wq, Wk, Wv.
// ---------------------------------------------------------------------------
__global__ __launch_bounds__(256) void to_bf16_all(
    const float* __restrict__ x,  const float* __restrict__ wq,
    const float* __restrict__ wk, const float* __restrict__ wv,
    unsigned short* __restrict__ xb,  unsigned short* __restrict__ wqb,
    unsigned short* __restrict__ wkb, unsigned short* __restrict__ wvb)
{
    const size_t TX = (size_t)NB * NS * ND / 8;
    const size_t TW = (size_t)ND * ND / 8;
    size_t gid = (size_t)blockIdx.x * 256 + threadIdx.x;
    const float* src; unsigned short* dst; size_t off;
    if (gid < TX)               { src = x;  dst = xb;  off = gid * 8; }
    else if (gid < TX + TW)     { src = wq; dst = wqb; off = (gid - TX) * 8; }
    else if (gid < TX + 2 * TW) { src = wk; dst = wkb; off = (gid - TX - TW) * 8; }
    else                        { src = wv; dst = wvb; off = (gid - TX - 2 * TW) * 8; }
    float4 a = *(const float4*)(src + off);
    float4 b = *(const float4*)(src + off + 4);
    alignas(16) unsigned short t[8];
    t[0] = f2b(a.x); t[1] = f2b(a.y); t[2] = f2b(a.z); t[3] = f2b(a.w);
    t[4] = f2b(b.x); t[5] = f2b(b.y); t[6] = f2b(b.z); t[7] = f2b(b.w);
    *(uint4*)(dst + off) = *(const uint4*)t;
}

// ---------------------------------------------------------------------------
// Mask dtype probe. flag = 1 -> 4-byte elements, 0 -> 1-byte.
// ---------------------------------------------------------------------------
__global__ void detect_mask(const unsigned* __restrict__ m, int* __restrict__ flag) {
    __shared__ int bad;
    if (threadIdx.x == 0) bad = 0;
    __syncthreads();
    int mybad = 0;
    for (int i = threadIdx.x; i < 8192; i += 256) {
        unsigned w = m[i];
        if (w != 0u && w != 1u && w != 0x3F800000u) mybad = 1;
    }
    if (mybad) bad = 1;
    __syncthreads();
    if (threadIdx.x == 0) *flag = bad ? 0 : 1;
}

// ---------------------------------------------------------------------------
// Bit-pack the mask -> u64 words (1 MB, L2-resident).
// ---------------------------------------------------------------------------
__global__ __launch_bounds__(256) void pack_mask(
    const void* __restrict__ mask, const int* __restrict__ mflag,
    unsigned long long* __restrict__ mbits)
{
    const int wave = threadIdx.x >> 6;
    const int lane = threadIdx.x & 63;
    const size_t w = (size_t)blockIdx.x * 4 + wave;
    const size_t e = w * 64 + lane;
    int v;
    if (*mflag) v = (((const unsigned*)mask)[e] != 0u);
    else        v = (((const unsigned char*)mask)[e] != 0);
    unsigned long long bits = __ballot(v);
    if (lane == 0) mbits[w] = bits;
}

// ---------------------------------------------------------------------------
// QKV projection, m97-style staging: global_load_lds(16B) into linear LDS
// with pre-swizzled source; XOR-swizzled ds_read (conflict-free).
// LDS tile [128 rows][32 shorts]; seg' = seg ^ ((row>>1)&3).
// ---------------------------------------------------------------------------
__global__ __launch_bounds__(256) void qkv_gemm(
    const unsigned short* __restrict__ xb,
    const unsigned short* __restrict__ Wqb, const float* __restrict__ bq,
    const unsigned short* __restrict__ Wkb, const float* __restrict__ bk,
    const unsigned short* __restrict__ Wvb, const float* __restrict__ bv,
    unsigned short* __restrict__ Qb, unsigned short* __restrict__ Kb,
    unsigned short* __restrict__ Vtb)
{
    __shared__ alignas(16) unsigned short Alds[128 * 32];
    __shared__ alignas(16) unsigned short Blds[128 * 32];

    const int tid  = threadIdx.x;
    const int wave = tid >> 6;
    const int lane = tid & 63;
    const int z    = blockIdx.z;

    const unsigned short* W = (z == 0) ? Wqb : (z == 1) ? Wkb : Wvb;
    const float* bias       = (z == 0) ? bq  : (z == 1) ? bk  : bv;

    const int m0 = blockIdx.x * 128;
    const int n0 = blockIdx.y * 128;
    const int wr = (wave >> 1) * 64;
    const int wc = (wave & 1) * 64;

    // staging invariants: instr i covers 16B-slots i*256+tid; slot s ->
    // row = s>>2, seg = s&3; source seg pre-swizzled.
    const int r0 = tid >> 2;
    const int r1 = 64 + (tid >> 2);
    const int ss = tid & 3;
    const int aoff0 = r0 * ND + ((ss ^ ((r0 >> 1) & 3)) * 8);
    const int aoff1 = r1 * ND + ((ss ^ ((r1 >> 1) & 3)) * 8);
    unsigned short* ldsA0 = Alds + wave * 512;
    unsigned short* ldsA1 = Alds + 2048 + wave * 512;
    unsigned short* ldsB0 = Blds + wave * 512;
    unsigned short* ldsB1 = Blds + 2048 + wave * 512;

    const unsigned short* xsrc = xb + (size_t)m0 * ND;
    const unsigned short* wsrc = W  + (size_t)n0 * ND;

    const int lg = lane >> 4;
    const int ll = lane & 15;
    // frag read: row = base + ll, byte = row*64 + (lg ^ ((ll>>1)&3))*16
    const int segb = (lg ^ ((ll >> 1) & 3)) * 16;

    f32x4 acc[4][4] = {};

    for (int kt = 0; kt < ND; kt += 32) {
        if (kt != 0) __syncthreads();
        gl_lds16(xsrc + kt + aoff0, ldsA0);
        gl_lds16(xsrc + kt + aoff1, ldsA1);
        gl_lds16(wsrc + kt + aoff0, ldsB0);
        gl_lds16(wsrc + kt + aoff1, ldsB1);
        __syncthreads();   // compiler drains vmcnt(0) before barrier

        bf16x8 af[4], bfr[4];
        #pragma unroll
        for (int m = 0; m < 4; m++)
            af[m] = *(const bf16x8*)((const char*)Alds
                     + (wr + m * 16 + ll) * 64 + segb);
        #pragma unroll
        for (int n = 0; n < 4; n++)
            bfr[n] = *(const bf16x8*)((const char*)Blds
                     + (wc + n * 16 + ll) * 64 + segb);

        #pragma unroll
        for (int m = 0; m < 4; m++)
            #pragma unroll
            for (int n = 0; n < 4; n++)
                acc[m][n] = __builtin_amdgcn_mfma_f32_16x16x32_bf16(
                    af[m], bfr[n], acc[m][n], 0, 0, 0);
    }

    #pragma unroll
    for (int n = 0; n < 4; n++) {
        const int j  = n0 + wc + n * 16 + ll;
        const float bj = bias[j];
        const int hh = j >> 6;
        const int hd = j & 63;
        #pragma unroll
        for (int m = 0; m < 4; m++) {
            #pragma unroll
            for (int r = 0; r < 4; r++) {
                const int i  = m0 + wr + m * 16 + lg * 4 + r;
                const int bb = i >> 11;
                const int sI = i & 2047;
                const unsigned short o = f2b(acc[m][n][r] + bj);
                if (z == 2) {
                    Vtb[((size_t)(bb * NH + hh) * NHD + hd) * NS + sI] = o;
                } else {
                    const size_t idx = ((size_t)(bb * NH + hh) * NS + sI) * NHD + hd;
                    if (z == 0) Qb[idx] = o; else Kb[idx] = o;
                }
            }
        }
    }
}

// ---------------------------------------------------------------------------
// Flash attention, 8-wave blocks: K/V tiles staged ONCE per block into LDS
// (global_load_lds, pre-swizzled source) and shared by all 8 waves — removes
// the 8x-redundant per-wave L2 fragment traffic of rounds 2-5.
// Tile [64 rows][64 shorts = 8 segs]; LDS(row, seg) holds global
// (row, seg ^ (row&7)); frag read XORs the same term -> 8 bank-quads x 8
// lanes = minimum-phase b128 reads.
// Softmax: swapped-QK^T register path (round 5, verified).
// ---------------------------------------------------------------------------
__global__ __launch_bounds__(512, 4) void attn_kernel(
    const unsigned short* __restrict__ Qb, const unsigned short* __restrict__ Kb,
    const unsigned short* __restrict__ Vtb,
    const unsigned long long* __restrict__ mbits, float* __restrict__ out)
{
    __shared__ alignas(16) unsigned short Kt[64 * 64];
    __shared__ alignas(16) unsigned short Vt[64 * 64];
    __shared__ alignas(16) unsigned short Plds[8][16][72];

    const int tid  = threadIdx.x;
    const int wave = tid >> 6;
    const int lane = tid & 63;

    // XCD-bijective decode: 512 wgs, 4 heads per XCD, 16 q-blocks per head.
    const int wg   = blockIdx.x;
    const int xcd  = wg & 7;
    const int slot = wg >> 3;                // 0..63
    const int hb   = xcd * 4 + (slot >> 4);  // 0..31
    const int qblk = slot & 15;
    const int h = hb & (NH - 1);
    const int b = hb >> 4;
    const int q0 = qblk * 128 + wave * 16;

    const unsigned short* Qp = Qb  + (size_t)(b * NH + h) * NS * NHD;
    const unsigned short* Kp = Kb  + (size_t)(b * NH + h) * NS * NHD;
    const unsigned short* Vp = Vtb + (size_t)(b * NH + h) * NHD * NS;
    const unsigned long long* mrow = mbits + (size_t)b * NS * (NS / 64);

    const int lg = lane >> 4;
    const int ll = lane & 15;

    // staging invariants: this lane stages tile row rw, source seg pre-swizzled
    const int rw = wave * 8 + (lane >> 3);
    const int sg = (lane & 7) ^ (rw & 7);
    const size_t ksoff = (size_t)rw * NHD + sg * 8;
    const size_t vsoff = (size_t)rw * NS  + sg * 8;
    unsigned short* ldsK = Kt + wave * 512;
    unsigned short* ldsV = Vt + wave * 512;

    // frag-read byte offsets within a tile (row ll-based, XOR-deswizzled)
    const int xr7 = ll & 7;
    const int ka0 = ll * 128 + ((lg)     ^ xr7) * 16;   // k/d segs 0..31
    const int ka1 = ll * 128 + ((lg + 4) ^ xr7) * 16;   // segs 32..63

    // Q fragments (B-operand), hoisted
    const int kcol = lg * 8;
    const bf16x8 qf0 = *(const bf16x8*)&Qp[(q0 + ll) * NHD + kcol];
    const bf16x8 qf1 = *(const bf16x8*)&Qp[(q0 + ll) * NHD + 32 + kcol];

    f32x4 O0 = {}, O1 = {}, O2 = {}, O3 = {};
    float mrun = -3.0e38f;   // running max for q = q0 + ll
    float lrun = 0.f;

    const float scale = 0.03125f;  // 1/sqrt(1024)

    unsigned long long mwc = mrow[(size_t)(q0 + ll) * (NS / 64)];

    for (int t = 0; t < 32; t++) {
        const int kb = t * 64;
        // ---- stage K/V tiles (shared by all 8 waves) ----
        if (t != 0) __syncthreads();           // all waves done reading prev tile
        gl_lds16(Kp + (size_t)kb * NHD + ksoff, ldsK);
        gl_lds16(Vp + kb + vsoff, ldsV);
        // prefetch next mask word while loads are in flight
        const int tn = (t + 1 < 32) ? t + 1 : 0;
        const unsigned long long mwn = mrow[(size_t)(q0 + ll) * (NS / 64) + tn];
        __syncthreads();                        // vmcnt(0) drain -> tiles ready

        // ---- K fragments from LDS, QK^T swapped ----
        f32x4 s0 = {}, s1 = {}, s2 = {}, s3 = {};
        {
            const bf16x8 k00 = *(const bf16x8*)((const char*)Kt + 0 * 2048 + ka0);
            const bf16x8 k10 = *(const bf16x8*)((const char*)Kt + 1 * 2048 + ka0);
            const bf16x8 k20 = *(const bf16x8*)((const char*)Kt + 2 * 2048 + ka0);
            const bf16x8 k30 = *(const bf16x8*)((const char*)Kt + 3 * 2048 + ka0);
            s0 = __builtin_amdgcn_mfma_f32_16x16x32_bf16(k00, qf0, s0, 0, 0, 0);
            s1 = __builtin_amdgcn_mfma_f32_16x16x32_bf16(k10, qf0, s1, 0, 0, 0);
            s2 = __builtin_amdgcn_mfma_f32_16x16x32_bf16(k20, qf0, s2, 0, 0, 0);
            s3 = __builtin_amdgcn_mfma_f32_16x16x32_bf16(k30, qf0, s3, 0, 0, 0);
            const bf16x8 k01 = *(const bf16x8*)((const char*)Kt + 0 * 2048 + ka1);
            const bf16x8 k11 = *(const bf16x8*)((const char*)Kt + 1 * 2048 + ka1);
            const bf16x8 k21 = *(const bf16x8*)((const char*)Kt + 2 * 2048 + ka1);
            const bf16x8 k31 = *(const bf16x8*)((const char*)Kt + 3 * 2048 + ka1);
            s0 = __builtin_amdgcn_mfma_f32_16x16x32_bf16(k01, qf1, s0, 0, 0, 0);
            s1 = __builtin_amdgcn_mfma_f32_16x16x32_bf16(k11, qf1, s1, 0, 0, 0);
            s2 = __builtin_amdgcn_mfma_f32_16x16x32_bf16(k21, qf1, s2, 0, 0, 0);
            s3 = __builtin_amdgcn_mfma_f32_16x16x32_bf16(k31, qf1, s3, 0, 0, 0);
        }

        // ---- scores for q=q0+ll: sv[tt*4+r] = score(k = kb + 16tt + 4lg + r) ----
        const unsigned long long mws = mwc >> (lg * 4);
        float sv[16];
        #pragma unroll
        for (int tt = 0; tt < 4; tt++) {
            const f32x4 st = (tt == 0) ? s0 : (tt == 1) ? s1 : (tt == 2) ? s2 : s3;
            #pragma unroll
            for (int r = 0; r < 4; r++)
                sv[tt * 4 + r] = ((mws >> (16 * tt + r)) & 1ull) ? -1e9f
                                                                 : st[r] * scale;
        }

        float m01 = fmaxf(fmaxf(sv[0], sv[1]), fmaxf(sv[2], sv[3]));
        float m23 = fmaxf(fmaxf(sv[4], sv[5]), fmaxf(sv[6], sv[7]));
        float m45 = fmaxf(fmaxf(sv[8], sv[9]), fmaxf(sv[10], sv[11]));
        float m67 = fmaxf(fmaxf(sv[12], sv[13]), fmaxf(sv[14], sv[15]));
        float mt = fmaxf(fmaxf(m01, m23), fmaxf(m45, m67));
        mt = fmaxf(mt, __shfl_xor(mt, 16));
        mt = fmaxf(mt, __shfl_xor(mt, 32));

        if (!__all(mt <= mrun + 8.0f)) {
            const float mnew  = fmaxf(mrun, mt);
            const float alpha = __expf(mrun - mnew);
            mrun = mnew;
            lrun *= alpha;
            #pragma unroll
            for (int r = 0; r < 4; r++) {
                const float ar = __shfl(alpha, lg * 4 + r);
                O0[r] *= ar; O1[r] *= ar; O2[r] *= ar; O3[r] *= ar;
            }
        }

        // ---- exp + sum + pack P ----
        float rs = 0.f;
        #pragma unroll
        for (int tt = 0; tt < 4; tt++) {
            const float p0 = __expf(sv[tt * 4 + 0] - mrun);
            const float p1 = __expf(sv[tt * 4 + 1] - mrun);
            const float p2 = __expf(sv[tt * 4 + 2] - mrun);
            const float p3 = __expf(sv[tt * 4 + 3] - mrun);
            rs += (p0 + p1) + (p2 + p3);
            uint2 w;
            w.x = (unsigned)f2b(p0) | ((unsigned)f2b(p1) << 16);
            w.y = (unsigned)f2b(p2) | ((unsigned)f2b(p3) << 16);
            *(uint2*)&Plds[wave][ll][tt * 16 + lg * 4] = w;
        }
        rs += __shfl_xor(rs, 16);
        rs += __shfl_xor(rs, 32);
        lrun += rs;

        // ---- PV: A = P from per-wave LDS slice, B = V^T frags from tile ----
        const bf16x8 pa0 = *(const bf16x8*)&Plds[wave][ll][kcol];
        const bf16x8 pa1 = *(const bf16x8*)&Plds[wave][ll][32 + kcol];
        {
            const bf16x8 v00 = *(const bf16x8*)((const char*)Vt + 0 * 2048 + ka0);
            const bf16x8 v10 = *(const bf16x8*)((const char*)Vt + 1 * 2048 + ka0);
            const bf16x8 v20 = *(const bf16x8*)((const char*)Vt + 2 * 2048 + ka0);
            const bf16x8 v30 = *(const bf16x8*)((const char*)Vt + 3 * 2048 + ka0);
            O0 = __builtin_amdgcn_mfma_f32_16x16x32_bf16(pa0, v00, O0, 0, 0, 0);
            O1 = __builtin_amdgcn_mfma_f32_16x16x32_bf16(pa0, v10, O1, 0, 0, 0);
            O2 = __builtin_amdgcn_mfma_f32_16x16x32_bf16(pa0, v20, O2, 0, 0, 0);
            O3 = __builtin_amdgcn_mfma_f32_16x16x32_bf16(pa0, v30, O3, 0, 0, 0);
            const bf16x8 v01 = *(const bf16x8*)((const char*)Vt + 0 * 2048 + ka1);
            const bf16x8 v11 = *(const bf16x8*)((const char*)Vt + 1 * 2048 + ka1);
            const bf16x8 v21 = *(const bf16x8*)((const char*)Vt + 2 * 2048 + ka1);
            const bf16x8 v31 = *(const bf16x8*)((const char*)Vt + 3 * 2048 + ka1);
            O0 = __builtin_amdgcn_mfma_f32_16x16x32_bf16(pa1, v01, O0, 0, 0, 0);
            O1 = __builtin_amdgcn_mfma_f32_16x16x32_bf16(pa1, v11, O1, 0, 0, 0);
            O2 = __builtin_amdgcn_mfma_f32_16x16x32_bf16(pa1, v21, O2, 0, 0, 0);
            O3 = __builtin_amdgcn_mfma_f32_16x16x32_bf16(pa1, v31, O3, 0, 0, 0);
        }
        mwc = mwn;
    }

    #pragma unroll
    for (int r = 0; r < 4; r++) {
        const int q = q0 + lg * 4 + r;
        const float inv = 1.0f / __shfl(lrun, lg * 4 + r);
        float* op = out + (size_t)(b * NS + q) * ND + h * NHD;
        op[0 * 16 + ll] = O0[r] * inv;
        op[1 * 16 + ll] = O1[r] * inv;
        op[2 * 16 + ll] = O2[r] * inv;
        op[3 * 16 + ll] = O3[r] * inv;
    }
}

extern "C" void kernel_launch(void* const* d_in, const int* in_sizes, int n_in,
                              void* d_out, int out_size, void* d_ws, size_t ws_size,
                              hipStream_t stream)
{
    const float* x  = (const float*)d_in[0];
    const void* mask = d_in[1];
    const float* Wq = (const float*)d_in[2];
    const float* bq = (const float*)d_in[3];
    const float* Wk = (const float*)d_in[4];
    const float* bk = (const float*)d_in[5];
    const float* Wv = (const float*)d_in[6];
    const float* bv = (const float*)d_in[7];
    float* out = (float*)d_out;

    const size_t szX = (size_t)NB * NS * ND;
    const size_t szW = (size_t)ND * ND;
    const size_t szQ = (size_t)NB * NH * NS * NHD;

    int* mflag = (int*)d_ws;
    unsigned short* xb  = (unsigned short*)((char*)d_ws + 256);
    unsigned short* Wqb = xb  + szX;
    unsigned short* Wkb = Wqb + szW;
    unsigned short* Wvb = Wkb + szW;
    unsigned short* Qb  = Wvb + szW;
    unsigned short* Kb  = Qb + szQ;
    unsigned short* Vtb = Kb + szQ;
    unsigned long long* mbits = (unsigned long long*)(Vtb + szQ);

    dim3 blk(256);
    const int cvtBlocks = (int)((szX + 3 * szW) / 8 / 256);
    to_bf16_all<<<dim3(cvtBlocks), blk, 0, stream>>>(
        x, Wq, Wk, Wv, xb, Wqb, Wkb, Wvb);

    detect_mask<<<dim3(1), blk, 0, stream>>>((const unsigned*)mask, mflag);
    const int words = NB * NS * NS / 64;
    pack_mask<<<dim3(words / 4), blk, 0, stream>>>(mask, mflag, mbits);

    dim3 g1(32, 8, 3);
    qkv_gemm<<<g1, blk, 0, stream>>>(xb, Wqb, bq, Wkb, bk, Wvb, bv, Qb, Kb, Vtb);

    attn_kernel<<<dim3(512), dim3(512), 0, stream>>>(Qb, Kb, Vtb, mbits, out);
}

// Round 9
// 234.367 us; speedup vs baseline: 1.7854x; 1.0028x over previous
//
#include <hip/hip_runtime.h>
#include <hip/hip_bf16.h>

typedef __bf16 bf16x8 __attribute__((ext_vector_type(8)));
typedef float f32x4 __attribute__((ext_vector_type(4)));

// Problem constants: B=2, S=2048, D=1024, H=16, HD=64
#define NB 2
#define NS 2048
#define ND 1024
#define NH 16
#define NHD 64

__device__ __forceinline__ unsigned short f2b(float f) {
    union { __hip_bfloat16 h; unsigned short u; } c;
    c.h = __float2bfloat16(f);
    return c.u;
}

// Async global->LDS, 16 bytes per lane. LDS dest = wave-uniform base + lane*16.
__device__ __forceinline__ void gl_lds16(const unsigned short* g, unsigned short* l) {
    __builtin_amdgcn_global_load_lds(
        (const __attribute__((address_space(1))) unsigned int*)g,
        (__attribute__((address_space(3))) unsigned int*)l, 16, 0, 0);
}

// ---------------------------------------------------------------------------
// One-shot f32->bf16 convert of x, Wq, Wk, Wv.
// ---------------------------------------------------------------------------
__global__ __launch_bounds__(256) void to_bf16_all(
    const float* __restrict__ x,  const float* __restrict__ wq,
    const float* __restrict__ wk, const float* __restrict__ wv,
    unsigned short* __restrict__ xb,  unsigned short* __restrict__ wqb,
    unsigned short* __restrict__ wkb, unsigned short* __restrict__ wvb)
{
    const size_t TX = (size_t)NB * NS * ND / 8;
    const size_t TW = (size_t)ND * ND / 8;
    size_t gid = (size_t)blockIdx.x * 256 + threadIdx.x;
    const float* src; unsigned short* dst; size_t off;
    if (gid < TX)               { src = x;  dst = xb;  off = gid * 8; }
    else if (gid < TX + TW)     { src = wq; dst = wqb; off = (gid - TX) * 8; }
    else if (gid < TX + 2 * TW) { src = wk; dst = wkb; off = (gid - TX - TW) * 8; }
    else                        { src = wv; dst = wvb; off = (gid - TX - 2 * TW) * 8; }
    float4 a = *(const float4*)(src + off);
    float4 b = *(const float4*)(src + off + 4);
    alignas(16) unsigned short t[8];
    t[0] = f2b(a.x); t[1] = f2b(a.y); t[2] = f2b(a.z); t[3] = f2b(a.w);
    t[4] = f2b(b.x); t[5] = f2b(b.y); t[6] = f2b(b.z); t[7] = f2b(b.w);
    *(uint4*)(dst + off) = *(const uint4*)t;
}

// ---------------------------------------------------------------------------
// Mask dtype probe. flag = 1 -> 4-byte elements, 0 -> 1-byte.
// ---------------------------------------------------------------------------
__global__ void detect_mask(const unsigned* __restrict__ m, int* __restrict__ flag) {
    __shared__ int bad;
    if (threadIdx.x == 0) bad = 0;
    __syncthreads();
    int mybad = 0;
    for (int i = threadIdx.x; i < 8192; i += 256) {
        unsigned w = m[i];
        if (w != 0u && w != 1u && w != 0x3F800000u) mybad = 1;
    }
    if (mybad) bad = 1;
    __syncthreads();
    if (threadIdx.x == 0) *flag = bad ? 0 : 1;
}

// ---------------------------------------------------------------------------
// Bit-pack the mask -> u64 words (1 MB, L2-resident).
// ---------------------------------------------------------------------------
__global__ __launch_bounds__(256) void pack_mask(
    const void* __restrict__ mask, const int* __restrict__ mflag,
    unsigned long long* __restrict__ mbits)
{
    const int wave = threadIdx.x >> 6;
    const int lane = threadIdx.x & 63;
    const size_t w = (size_t)blockIdx.x * 4 + wave;
    const size_t e = w * 64 + lane;
    int v;
    if (*mflag) v = (((const unsigned*)mask)[e] != 0u);
    else        v = (((const unsigned char*)mask)[e] != 0);
    unsigned long long bits = __ballot(v);
    if (lane == 0) mbits[w] = bits;
}

// ---------------------------------------------------------------------------
// QKV projection, m97 structure: 128x128 tile, K-step 64 (one barrier pair,
// 8 global_load_lds x16B, 16 ds_read_b128, 32 MFMA per step).
// LDS tile [128 rows][64 shorts = 8 segs]; LDS(row,seg) holds global
// (row, seg^(row&7)); read seg = (kk*4+lg)^(ll&7) -> conflict-free.
// Q output is pre-scaled by 1/sqrt(D) (folded out of the attn softmax).
// Q,K stored [B,H,S,HD] bf16; V stored transposed [B,H,HD,S] bf16.
// ---------------------------------------------------------------------------
__global__ __launch_bounds__(256) void qkv_gemm(
    const unsigned short* __restrict__ xb,
    const unsigned short* __restrict__ Wqb, const float* __restrict__ bq,
    const unsigned short* __restrict__ Wkb, const float* __restrict__ bk,
    const unsigned short* __restrict__ Wvb, const float* __restrict__ bv,
    unsigned short* __restrict__ Qb, unsigned short* __restrict__ Kb,
    unsigned short* __restrict__ Vtb)
{
    __shared__ alignas(16) unsigned short Alds[128 * 64];
    __shared__ alignas(16) unsigned short Blds[128 * 64];

    const int tid  = threadIdx.x;
    const int wave = tid >> 6;
    const int lane = tid & 63;
    const int z    = blockIdx.z;

    const unsigned short* W = (z == 0) ? Wqb : (z == 1) ? Wkb : Wvb;
    const float* bias       = (z == 0) ? bq  : (z == 1) ? bk  : bv;

    const int m0 = blockIdx.x * 128;
    const int n0 = blockIdx.y * 128;
    const int wr = (wave >> 1) * 64;
    const int wc = (wave & 1) * 64;

    // staging: instr i covers 16B-slots i*256+tid; slot s -> row=s>>3, seg=s&7
    int soff[4];
    #pragma unroll
    for (int i = 0; i < 4; i++) {
        const int r = i * 32 + (tid >> 3);
        soff[i] = r * ND + (((tid & 7) ^ (r & 7)) * 8);
    }

    const unsigned short* xsrc = xb + (size_t)m0 * ND;
    const unsigned short* wsrc = W  + (size_t)n0 * ND;

    const int lg = lane >> 4;
    const int ll = lane & 15;
    const int xr7 = ll & 7;

    f32x4 acc[4][4] = {};

    for (int kt = 0; kt < ND; kt += 64) {
        if (kt != 0) __syncthreads();
        #pragma unroll
        for (int i = 0; i < 4; i++) {
            gl_lds16(xsrc + kt + soff[i], Alds + i * 2048 + wave * 512);
            gl_lds16(wsrc + kt + soff[i], Blds + i * 2048 + wave * 512);
        }
        __syncthreads();   // compiler drains vmcnt(0) before barrier

        #pragma unroll
        for (int kk = 0; kk < 2; kk++) {
            const int segb = ((kk * 4 + lg) ^ xr7) * 16;
            bf16x8 af[4], bfr[4];
            #pragma unroll
            for (int m = 0; m < 4; m++)
                af[m] = *(const bf16x8*)((const char*)Alds
                         + (wr + m * 16 + ll) * 128 + segb);
            #pragma unroll
            for (int n = 0; n < 4; n++)
                bfr[n] = *(const bf16x8*)((const char*)Blds
                         + (wc + n * 16 + ll) * 128 + segb);

            #pragma unroll
            for (int m = 0; m < 4; m++)
                #pragma unroll
                for (int n = 0; n < 4; n++)
                    acc[m][n] = __builtin_amdgcn_mfma_f32_16x16x32_bf16(
                        af[m], bfr[n], acc[m][n], 0, 0, 0);
        }
    }

    const float oscale = (z == 0) ? 0.03125f : 1.0f;   // 1/sqrt(1024) into Q
    #pragma unroll
    for (int n = 0; n < 4; n++) {
        const int j  = n0 + wc + n * 16 + ll;
        const float bj = bias[j];
        const int hh = j >> 6;
        const int hd = j & 63;
        #pragma unroll
        for (int m = 0; m < 4; m++) {
            #pragma unroll
            for (int r = 0; r < 4; r++) {
                const int i  = m0 + wr + m * 16 + lg * 4 + r;
                const int bb = i >> 11;
                const int sI = i & 2047;
                const unsigned short o = f2b((acc[m][n][r] + bj) * oscale);
                if (z == 2) {
                    Vtb[((size_t)(bb * NH + hh) * NHD + hd) * NS + sI] = o;
                } else {
                    const size_t idx = ((size_t)(bb * NH + hh) * NS + sI) * NHD + hd;
                    if (z == 0) Qb[idx] = o; else Kb[idx] = o;
                }
            }
        }
    }
}

// ---------------------------------------------------------------------------
// Flash attention, 8-wave blocks, LDS-shared K/V tiles (round-8 verified).
// Q comes pre-scaled by 1/sqrt(D) -> no per-score multiply in softmax.
// ---------------------------------------------------------------------------
__global__ __launch_bounds__(512, 4) void attn_kernel(
    const unsigned short* __restrict__ Qb, const unsigned short* __restrict__ Kb,
    const unsigned short* __restrict__ Vtb,
    const unsigned long long* __restrict__ mbits, float* __restrict__ out)
{
    __shared__ alignas(16) unsigned short Kt[64 * 64];
    __shared__ alignas(16) unsigned short Vt[64 * 64];
    __shared__ alignas(16) unsigned short Plds[8][16][72];

    const int tid  = threadIdx.x;
    const int wave = tid >> 6;
    const int lane = tid & 63;

    // XCD-bijective decode: 512 wgs, 4 heads per XCD, 16 q-blocks per head.
    const int wg   = blockIdx.x;
    const int xcd  = wg & 7;
    const int slot = wg >> 3;                // 0..63
    const int hb   = xcd * 4 + (slot >> 4);  // 0..31
    const int qblk = slot & 15;
    const int h = hb & (NH - 1);
    const int b = hb >> 4;
    const int q0 = qblk * 128 + wave * 16;

    const unsigned short* Qp = Qb  + (size_t)(b * NH + h) * NS * NHD;
    const unsigned short* Kp = Kb  + (size_t)(b * NH + h) * NS * NHD;
    const unsigned short* Vp = Vtb + (size_t)(b * NH + h) * NHD * NS;
    const unsigned long long* mrow = mbits + (size_t)b * NS * (NS / 64);

    const int lg = lane >> 4;
    const int ll = lane & 15;

    // staging invariants: this lane stages tile row rw, source seg pre-swizzled
    const int rw = wave * 8 + (lane >> 3);
    const int sg = (lane & 7) ^ (rw & 7);
    const size_t ksoff = (size_t)rw * NHD + sg * 8;
    const size_t vsoff = (size_t)rw * NS  + sg * 8;
    unsigned short* ldsK = Kt + wave * 512;
    unsigned short* ldsV = Vt + wave * 512;

    // frag-read byte offsets within a tile (row ll-based, XOR-deswizzled)
    const int xr7 = ll & 7;
    const int ka0 = ll * 128 + ((lg)     ^ xr7) * 16;   // k/d segs 0..31
    const int ka1 = ll * 128 + ((lg + 4) ^ xr7) * 16;   // segs 32..63

    // Q fragments (B-operand), hoisted
    const int kcol = lg * 8;
    const bf16x8 qf0 = *(const bf16x8*)&Qp[(q0 + ll) * NHD + kcol];
    const bf16x8 qf1 = *(const bf16x8*)&Qp[(q0 + ll) * NHD + 32 + kcol];

    f32x4 O0 = {}, O1 = {}, O2 = {}, O3 = {};
    float mrun = -3.0e38f;   // running max for q = q0 + ll
    float lrun = 0.f;

    unsigned long long mwc = mrow[(size_t)(q0 + ll) * (NS / 64)];

    for (int t = 0; t < 32; t++) {
        const int kb = t * 64;
        // ---- stage K/V tiles (shared by all 8 waves) ----
        if (t != 0) __syncthreads();           // all waves done reading prev tile
        gl_lds16(Kp + (size_t)kb * NHD + ksoff, ldsK);
        gl_lds16(Vp + kb + vsoff, ldsV);
        // prefetch next mask word while loads are in flight
        const int tn = (t + 1 < 32) ? t + 1 : 0;
        const unsigned long long mwn = mrow[(size_t)(q0 + ll) * (NS / 64) + tn];
        __syncthreads();                        // vmcnt(0) drain -> tiles ready

        // ---- K fragments from LDS, QK^T swapped ----
        f32x4 s0 = {}, s1 = {}, s2 = {}, s3 = {};
        {
            const bf16x8 k00 = *(const bf16x8*)((const char*)Kt + 0 * 2048 + ka0);
            const bf16x8 k10 = *(const bf16x8*)((const char*)Kt + 1 * 2048 + ka0);
            const bf16x8 k20 = *(const bf16x8*)((const char*)Kt + 2 * 2048 + ka0);
            const bf16x8 k30 = *(const bf16x8*)((const char*)Kt + 3 * 2048 + ka0);
            s0 = __builtin_amdgcn_mfma_f32_16x16x32_bf16(k00, qf0, s0, 0, 0, 0);
            s1 = __builtin_amdgcn_mfma_f32_16x16x32_bf16(k10, qf0, s1, 0, 0, 0);
            s2 = __builtin_amdgcn_mfma_f32_16x16x32_bf16(k20, qf0, s2, 0, 0, 0);
            s3 = __builtin_amdgcn_mfma_f32_16x16x32_bf16(k30, qf0, s3, 0, 0, 0);
            const bf16x8 k01 = *(const bf16x8*)((const char*)Kt + 0 * 2048 + ka1);
            const bf16x8 k11 = *(const bf16x8*)((const char*)Kt + 1 * 2048 + ka1);
            const bf16x8 k21 = *(const bf16x8*)((const char*)Kt + 2 * 2048 + ka1);
            const bf16x8 k31 = *(const bf16x8*)((const char*)Kt + 3 * 2048 + ka1);
            s0 = __builtin_amdgcn_mfma_f32_16x16x32_bf16(k01, qf1, s0, 0, 0, 0);
            s1 = __builtin_amdgcn_mfma_f32_16x16x32_bf16(k11, qf1, s1, 0, 0, 0);
            s2 = __builtin_amdgcn_mfma_f32_16x16x32_bf16(k21, qf1, s2, 0, 0, 0);
            s3 = __builtin_amdgcn_mfma_f32_16x16x32_bf16(k31, qf1, s3, 0, 0, 0);
        }

        // ---- scores for q=q0+ll (pre-scaled): sv[tt*4+r], k = kb+16tt+4lg+r ----
        const unsigned long long mws = mwc >> (lg * 4);
        float sv[16];
        #pragma unroll
        for (int tt = 0; tt < 4; tt++) {
            const f32x4 st = (tt == 0) ? s0 : (tt == 1) ? s1 : (tt == 2) ? s2 : s3;
            #pragma unroll
            for (int r = 0; r < 4; r++)
                sv[tt * 4 + r] = ((mws >> (16 * tt + r)) & 1ull) ? -1e9f : st[r];
        }

        float m01 = fmaxf(fmaxf(sv[0], sv[1]), fmaxf(sv[2], sv[3]));
        float m23 = fmaxf(fmaxf(sv[4], sv[5]), fmaxf(sv[6], sv[7]));
        float m45 = fmaxf(fmaxf(sv[8], sv[9]), fmaxf(sv[10], sv[11]));
        float m67 = fmaxf(fmaxf(sv[12], sv[13]), fmaxf(sv[14], sv[15]));
        float mt = fmaxf(fmaxf(m01, m23), fmaxf(m45, m67));
        mt = fmaxf(mt, __shfl_xor(mt, 16));
        mt = fmaxf(mt, __shfl_xor(mt, 32));

        if (!__all(mt <= mrun + 8.0f)) {
            const float mnew  = fmaxf(mrun, mt);
            const float alpha = __expf(mrun - mnew);
            mrun = mnew;
            lrun *= alpha;
            #pragma unroll
            for (int r = 0; r < 4; r++) {
                const float ar = __shfl(alpha, lg * 4 + r);
                O0[r] *= ar; O1[r] *= ar; O2[r] *= ar; O3[r] *= ar;
            }
        }

        // ---- exp + sum + pack P ----
        float rs = 0.f;
        #pragma unroll
        for (int tt = 0; tt < 4; tt++) {
            const float p0 = __expf(sv[tt * 4 + 0] - mrun);
            const float p1 = __expf(sv[tt * 4 + 1] - mrun);
            const float p2 = __expf(sv[tt * 4 + 2] - mrun);
            const float p3 = __expf(sv[tt * 4 + 3] - mrun);
            rs += (p0 + p1) + (p2 + p3);
            uint2 w;
            w.x = (unsigned)f2b(p0) | ((unsigned)f2b(p1) << 16);
            w.y = (unsigned)f2b(p2) | ((unsigned)f2b(p3) << 16);
            *(uint2*)&Plds[wave][ll][tt * 16 + lg * 4] = w;
        }
        rs += __shfl_xor(rs, 16);
        rs += __shfl_xor(rs, 32);
        lrun += rs;

        // ---- PV: A = P from per-wave LDS slice, B = V^T frags from tile ----
        const bf16x8 pa0 = *(const bf16x8*)&Plds[wave][ll][kcol];
        const bf16x8 pa1 = *(const bf16x8*)&Plds[wave][ll][32 + kcol];
        {
            const bf16x8 v00 = *(const bf16x8*)((const char*)Vt + 0 * 2048 + ka0);
            const bf16x8 v10 = *(const bf16x8*)((const char*)Vt + 1 * 2048 + ka0);
            const bf16x8 v20 = *(const bf16x8*)((const char*)Vt + 2 * 2048 + ka0);
            const bf16x8 v30 = *(const bf16x8*)((const char*)Vt + 3 * 2048 + ka0);
            O0 = __builtin_amdgcn_mfma_f32_16x16x32_bf16(pa0, v00, O0, 0, 0, 0);
            O1 = __builtin_amdgcn_mfma_f32_16x16x32_bf16(pa0, v10, O1, 0, 0, 0);
            O2 = __builtin_amdgcn_mfma_f32_16x16x32_bf16(pa0, v20, O2, 0, 0, 0);
            O3 = __builtin_amdgcn_mfma_f32_16x16x32_bf16(pa0, v30, O3, 0, 0, 0);
            const bf16x8 v01 = *(const bf16x8*)((const char*)Vt + 0 * 2048 + ka1);
            const bf16x8 v11 = *(const bf16x8*)((const char*)Vt + 1 * 2048 + ka1);
            const bf16x8 v21 = *(const bf16x8*)((const char*)Vt + 2 * 2048 + ka1);
            const bf16x8 v31 = *(const bf16x8*)((const char*)Vt + 3 * 2048 + ka1);
            O0 = __builtin_amdgcn_mfma_f32_16x16x32_bf16(pa1, v01, O0, 0, 0, 0);
            O1 = __builtin_amdgcn_mfma_f32_16x16x32_bf16(pa1, v11, O1, 0, 0, 0);
            O2 = __builtin_amdgcn_mfma_f32_16x16x32_bf16(pa1, v21, O2, 0, 0, 0);
            O3 = __builtin_amdgcn_mfma_f32_16x16x32_bf16(pa1, v31, O3, 0, 0, 0);
        }
        mwc = mwn;
    }

    #pragma unroll
    for (int r = 0; r < 4; r++) {
        const int q = q0 + lg * 4 + r;
        const float inv = 1.0f / __shfl(lrun, lg * 4 + r);
        float* op = out + (size_t)(b * NS + q) * ND + h * NHD;
        op[0 * 16 + ll] = O0[r] * inv;
        op[1 * 16 + ll] = O1[r] * inv;
        op[2 * 16 + ll] = O2[r] * inv;
        op[3 * 16 + ll] = O3[r] * inv;
    }
}

extern "C" void kernel_launch(void* const* d_in, const int* in_sizes, int n_in,
                              void* d_out, int out_size, void* d_ws, size_t ws_size,
                              hipStream_t stream)
{
    const float* x  = (const float*)d_in[0];
    const void* mask = d_in[1];
    const float* Wq = (const float*)d_in[2];
    const float* bq = (const float*)d_in[3];
    const float* Wk = (const float*)d_in[4];
    const float* bk = (const float*)d_in[5];
    const float* Wv = (const float*)d_in[6];
    const float* bv = (const float*)d_in[7];
    float* out = (float*)d_out;

    const size_t szX = (size_t)NB * NS * ND;
    const size_t szW = (size_t)ND * ND;
    const size_t szQ = (size_t)NB * NH * NS * NHD;

    int* mflag = (int*)d_ws;
    unsigned short* xb  = (unsigned short*)((char*)d_ws + 256);
    unsigned short* Wqb = xb  + szX;
    unsigned short* Wkb = Wqb + szW;
    unsigned short* Wvb = Wkb + szW;
    unsigned short* Qb  = Wvb + szW;
    unsigned short* Kb  = Qb + szQ;
    unsigned short* Vtb = Kb + szQ;
    unsigned long long* mbits = (unsigned long long*)(Vtb + szQ);

    dim3 blk(256);
    const int cvtBlocks = (int)((szX + 3 * szW) / 8 / 256);
    to_bf16_all<<<dim3(cvtBlocks), blk, 0, stream>>>(
        x, Wq, Wk, Wv, xb, Wqb, Wkb, Wvb);

    detect_mask<<<dim3(1), blk, 0, stream>>>((const unsigned*)mask, mflag);
    const int words = NB * NS * NS / 64;
    pack_mask<<<dim3(words / 4), blk, 0, stream>>>(mask, mflag, mbits);

    dim3 g1(32, 8, 3);
    qkv_gemm<<<g1, blk, 0, stream>>>(xb, Wqb, bq, Wkb, bk, Wvb, bv, Qb, Kb, Vtb);

    attn_kernel<<<dim3(512), dim3(512), 0, stream>>>(Qb, Kb, Vtb, mbits, out);
}